// Round 6
// baseline (210.822 us; speedup 1.0000x reference)
//
#include <hip/hip_runtime.h>

// Problem constants: B=4, S=4096, D=1024, H=64
#define NS 8       // attention key-range splits

typedef __attribute__((ext_vector_type(8))) short sh8;  // 8 x bf16 (4 VGPRs)
typedef __attribute__((ext_vector_type(4))) short sh4;  // 4 x bf16 (8 B)
typedef __attribute__((ext_vector_type(4))) float f4;   // MFMA accumulator

// fold 1/sqrt(64) * log2(e) into Q so softmax is pure exp2
#define QSCALE 0.18033688011112042f

static __device__ __forceinline__ unsigned short f2bf(float f) {
  unsigned u = __builtin_bit_cast(unsigned, f);
  u += 0x7fffu + ((u >> 16) & 1u);   // RNE
  return (unsigned short)(u >> 16);
}
static __device__ __forceinline__ float bf2f(unsigned short s) {
  unsigned u = ((unsigned)s) << 16;
  return __builtin_bit_cast(float, u);
}

// ---------------- kernel 1: Wt2 = W in MFMA B-fragment order ----------------
// Wt2[band][kt][lane][j] (bf16) band 0..11 (0-3 Q, 4-7 K, 8-11 V), kt 0..31,
// lane = q*16+l15 holds W[k = kt*32+q*8+j][col = band%4*16+l15].
__global__ __launch_bounds__(256) void wt_kernel(const float* __restrict__ Wq,
                                                 const float* __restrict__ Wk,
                                                 const float* __restrict__ Wv,
                                                 unsigned short* __restrict__ Wt2) {
  int blk = blockIdx.x;                 // 0..95
  int band = blk >> 3;                  // 0..11
  int widx = band >> 2;
  const float* W = widx == 0 ? Wq : (widx == 1 ? Wk : Wv);
  int ncol = (band & 3) * 16;
  int t = threadIdx.x;
  int kt = (blk & 7) * 4 + (t >> 6);    // 4 kt per block
  int lane = t & 63, q = lane >> 4, l15 = lane & 15;
  const float* src = W + (size_t)(kt * 32 + q * 8) * 64 + ncol + l15;
  sh8 o;
#pragma unroll
  for (int j = 0; j < 8; ++j) o[j] = (short)f2bf(src[(size_t)j * 64]);
  *(sh8*)&Wt2[((size_t)(band * 32 + kt) * 64 + lane) * 8] = o;
}

// ---------------- kernel 2: projection — pure-TLP, 12 waves/block, 1 band/wave ----------------
// R3-R5 post-mortem: every ILP/pipelining scheme was deleted (R4, VGPR=32), spilled
// (R5, WRITE_SIZE 68MB) or drained (R1/R2) by the compiler. This version hides latency
// with THREAD parallelism instead, which the compiler can't destroy:
//   grid 1024 blocks x 768 threads = 12288 waves (1.5x the 8192 wave slots; old: 4096).
//   Block = one 16-row A tile; wave w = output band w (12 bands). All 12 waves load
//   identical A fragments (L1 broadcast); each streams its own L2-resident 32KB B band.
// Inner loop left naive on purpose: 3 loads + pack + 1 MFMA, no hints. launch_bounds
// (768,6) caps VGPR at 85 -> 2 blocks/CU = 24 waves/CU resident.
__global__ __launch_bounds__(768, 6) void proj_kernel(const float* __restrict__ in,
                                                      const unsigned short* __restrict__ Wt2,
                                                      unsigned short* __restrict__ Qg,
                                                      unsigned short* __restrict__ Kg,
                                                      unsigned short* __restrict__ Vtg) {
  int t = threadIdx.x;
  int band = t >> 6, lane = t & 63, q = lane >> 4, l15 = lane & 15;
  int m0 = blockIdx.x * 16;

  const float* arow = in + (size_t)(m0 + l15) * 1024 + q * 8;
  const unsigned short* bbase = Wt2 + (size_t)band * 16384 + lane * 8;

  f4 acc = {0.f, 0.f, 0.f, 0.f};

#pragma unroll 4
  for (int kt = 0; kt < 32; ++kt) {
    f4 lo = *(const f4*)(arow + kt * 32);
    f4 hi = *(const f4*)(arow + kt * 32 + 4);
    sh8 b = *(const sh8*)(bbase + kt * 512);
    sh8 a;
#pragma unroll
    for (int j = 0; j < 4; ++j) {
      a[j] = (short)f2bf(lo[j]);
      a[4 + j] = (short)f2bf(hi[j]);
    }
    acc = __builtin_amdgcn_mfma_f32_16x16x32_bf16(a, b, acc, 0, 0, 0);
  }

  // store: C-tile row = q*4+r (input row), col = l15 within band.
  // bands 0-3 -> Q (scaled), 4-7 -> K, 8-11 -> V stored pre-transposed (packed sh4).
  int bb = m0 >> 12, s0 = m0 & 4095;
  if (band < 4) {
#pragma unroll
    for (int r = 0; r < 4; ++r)
      Qg[(size_t)(m0 + q * 4 + r) * 64 + band * 16 + l15] = f2bf(acc[r] * QSCALE);
  } else if (band < 8) {
#pragma unroll
    for (int r = 0; r < 4; ++r)
      Kg[(size_t)(m0 + q * 4 + r) * 64 + (band - 4) * 16 + l15] = f2bf(acc[r]);
  } else {
    int h = (band - 8) * 16 + l15;
    sh4 pv;
#pragma unroll
    for (int r = 0; r < 4; ++r) pv[r] = (short)f2bf(acc[r]);
    *(sh4*)&Vtg[(((size_t)(bb * 64 + h)) << 12) + s0 + q * 4] = pv;
  }
}

// ---------------- kernel 3: causal flash attention, S^T trick, split-K ----------------
__global__ __launch_bounds__(256, 4) void attn_split(const unsigned short* __restrict__ Qg,
                                                     const unsigned short* __restrict__ Kg,
                                                     const unsigned short* __restrict__ Vtg,
                                                     unsigned short* __restrict__ Opart,
                                                     float* __restrict__ Lpart) {
  __shared__ unsigned short Ks[64 * 72];
  __shared__ unsigned short Vs[64 * 72];
  __shared__ unsigned short Pw[4 * 16 * 72];
  int t = threadIdx.x;
  int b = blockIdx.y;
  int qt = 63 - (int)(blockIdx.x >> 3);  // heavy q-tiles first (LPT)
  int sp = blockIdx.x & 7;
  int wave = t >> 6, lane = t & 63, quad = lane >> 4, l15 = lane & 15;
  unsigned short* Pws = Pw + wave * 16 * 72;

  int qrow0 = qt * 64 + wave * 16;
  size_t pbase = ((size_t)sp * 4 + b) * 4096;

  int nkt = qt + 1;
  int chunk = (nkt + NS - 1) / NS;
  int t0 = sp * chunk, t1 = min(nkt, t0 + chunk);
  if (t0 >= t1) {  // empty chunk: zero partials
#pragma unroll
    for (int r = 0; r < 4; ++r) {
      size_t row = pbase + qrow0 + quad * 4 + r;
#pragma unroll
      for (int ht = 0; ht < 4; ++ht) Opart[row * 64 + ht * 16 + l15] = 0;
      if (l15 == 0) Lpart[row] = 0.f;
    }
    return;
  }

  sh8 qa[2];
#pragma unroll
  for (int ks = 0; ks < 2; ++ks)
    qa[ks] = *(const sh8*)&Qg[(size_t)((b << 12) + qrow0 + l15) * 64 + ks * 32 + quad * 8];

  sh8 ones;
#pragma unroll
  for (int j = 0; j < 8; ++j) ones[j] = (short)0x3F80;  // bf16 1.0

  f4 o[5];  // o[0..3]: O accumulator; o[4]: row-sum (P * ones)
  f4 z = {0.f, 0.f, 0.f, 0.f};
#pragma unroll
  for (int ht = 0; ht < 5; ++ht) o[ht] = z;

  // staging geometry: thread covers chunks c0=t, c1=t+256; row=c>>3, off=(c&7)*8
  int r0 = t >> 3, o0 = (t & 7) * 8;
  int r1 = (t + 256) >> 3, o1 = ((t + 256) & 7) * 8;
  const unsigned short* kg0 = Kg + (size_t)((b << 12) + r0) * 64 + o0;
  const unsigned short* kg1 = Kg + (size_t)((b << 12) + r1) * 64 + o1;
  const unsigned short* vg0 = Vtg + (((size_t)(b * 64 + r0)) << 12) + o0;
  const unsigned short* vg1 = Vtg + (((size_t)(b * 64 + r1)) << 12) + o1;

  sh8 kr0, kr1, vr0, vr1;
  {
    size_t ko = (size_t)t0 * 64 * 64;
    kr0 = *(const sh8*)(kg0 + ko); kr1 = *(const sh8*)(kg1 + ko);
    vr0 = *(const sh8*)(vg0 + t0 * 64); vr1 = *(const sh8*)(vg1 + t0 * 64);
  }

  for (int kt = t0; kt < t1; ++kt) {
    __syncthreads();                      // prev-iter LDS reads done
    *(sh8*)&Ks[r0 * 72 + o0] = kr0;
    *(sh8*)&Ks[r1 * 72 + o1] = kr1;
    *(sh8*)&Vs[r0 * 72 + o0] = vr0;
    *(sh8*)&Vs[r1 * 72 + o1] = vr1;
    if (kt + 1 < t1) {                    // prefetch next tile into regs
      size_t ko = (size_t)(kt + 1) * 64 * 64;
      kr0 = *(const sh8*)(kg0 + ko); kr1 = *(const sh8*)(kg1 + ko);
      vr0 = *(const sh8*)(vg0 + (kt + 1) * 64); vr1 = *(const sh8*)(vg1 + (kt + 1) * 64);
    }
    __syncthreads();                      // Ks/Vs visible

    // S^T = K * Q^T: st[nt] lane(quad,l15) reg r = S[qrow0+l15][kt*64+nt*16+quad*4+r]
    f4 st[4];
#pragma unroll
    for (int nt = 0; nt < 4; ++nt) st[nt] = z;
#pragma unroll
    for (int ks = 0; ks < 2; ++ks) {
#pragma unroll
      for (int nt = 0; nt < 4; ++nt) {
        sh8 kb = *(const sh8*)&Ks[(nt * 16 + l15) * 72 + ks * 32 + quad * 8];
        st[nt] = __builtin_amdgcn_mfma_f32_16x16x32_bf16(kb, qa[ks], st[nt], 0, 0, 0);
      }
    }

    if (kt == nkt - 1) {  // causal mask on the global diagonal tile
      int qrow = qrow0 + l15;
#pragma unroll
      for (int nt = 0; nt < 4; ++nt) {
        int key0 = kt * 64 + nt * 16 + quad * 4;
#pragma unroll
        for (int r = 0; r < 4; ++r)
          if (key0 + r > qrow) st[nt][r] = -__builtin_inff();
      }
    }

    // static-max softmax: P = exp2(S); pack 4 contiguous keys -> one b64 LDS write
#pragma unroll
    for (int nt = 0; nt < 4; ++nt) {
      sh4 pk;
#pragma unroll
      for (int r = 0; r < 4; ++r) pk[r] = (short)f2bf(exp2f(st[nt][r]));
      *(sh4*)&Pws[l15 * 72 + nt * 16 + quad * 4] = pk;
    }
    asm volatile("s_waitcnt lgkmcnt(0)" ::: "memory");

#pragma unroll
    for (int ks = 0; ks < 2; ++ks) {
      sh8 pa = *(const sh8*)&Pws[l15 * 72 + ks * 32 + quad * 8];
#pragma unroll
      for (int ht = 0; ht < 4; ++ht) {
        sh8 vb = *(const sh8*)&Vs[(ht * 16 + l15) * 72 + ks * 32 + quad * 8];
        o[ht] = __builtin_amdgcn_mfma_f32_16x16x32_bf16(pa, vb, o[ht], 0, 0, 0);
      }
      o[4] = __builtin_amdgcn_mfma_f32_16x16x32_bf16(pa, ones, o[4], 0, 0, 0);
    }
  }

  // write partials (unnormalized O, bf16; L fp32)
#pragma unroll
  for (int r = 0; r < 4; ++r) {
    size_t row = pbase + qrow0 + quad * 4 + r;
#pragma unroll
    for (int ht = 0; ht < 4; ++ht)
      Opart[row * 64 + ht * 16 + l15] = f2bf(o[ht][r]);
    if (l15 == 0) Lpart[row] = o[4][r];
  }
}

// ---------------- kernel 4: combine split partials ----------------
__global__ __launch_bounds__(256) void attn_combine(const unsigned short* __restrict__ Opart,
                                                    const float* __restrict__ Lpart,
                                                    float* __restrict__ out) {
  int t = threadIdx.x;
  int rg = blockIdx.x * 4 + (t >> 6);  // global row 0..16383
  int lane = t & 63;
  float acc = 0.f, L = 0.f;
#pragma unroll
  for (int s = 0; s < NS; ++s) {
    L += Lpart[(size_t)s * 16384 + rg];
    acc += bf2f(Opart[((size_t)s * 16384 + rg) * 64 + lane]);
  }
  out[(size_t)rg * 64 + lane] = acc / L;
}

extern "C" void kernel_launch(void* const* d_in, const int* in_sizes, int n_in,
                              void* d_out, int out_size, void* d_ws, size_t ws_size,
                              hipStream_t stream) {
  const float* in = (const float*)d_in[0];
  const float* Wq = (const float*)d_in[1];
  const float* Wk = (const float*)d_in[2];
  const float* Wv = (const float*)d_in[3];
  float* out = (float*)d_out;

  char* ws = (char*)d_ws;
  unsigned short* Wt2   = (unsigned short*)ws;                 // 393,216 B
  unsigned short* Qg    = (unsigned short*)(ws + 393216);      // 2 MiB
  unsigned short* Kg    = (unsigned short*)(ws + 2490368);     // 2 MiB
  unsigned short* Vtg   = (unsigned short*)(ws + 4587520);     // 2 MiB
  unsigned short* Opart = (unsigned short*)(ws + 6684672);     // 16,777,216 B
  float*          Lpart = (float*)(ws + 23461888);             // 524,288 B
  // total ws use ~24 MiB

  hipLaunchKernelGGL(wt_kernel, dim3(96), dim3(256), 0, stream, Wq, Wk, Wv, Wt2);
  hipLaunchKernelGGL(proj_kernel, dim3(1024), dim3(768), 0, stream, in, Wt2, Qg, Kg, Vtg);
  hipLaunchKernelGGL(attn_split, dim3(64 * NS, 4), dim3(256), 0, stream,
                     Qg, Kg, Vtg, Opart, Lpart);
  hipLaunchKernelGGL(attn_combine, dim3(4096), dim3(256), 0, stream,
                     Opart, Lpart, out);
}

// Round 7
// 153.701 us; speedup vs baseline: 1.3716x; 1.3716x over previous
//
#include <hip/hip_runtime.h>

// Problem constants: B=4, S=4096, D=1024, H=64
#define NS 8       // attention key-range splits

typedef __attribute__((ext_vector_type(8))) short sh8;  // 8 x bf16 (4 VGPRs)
typedef __attribute__((ext_vector_type(4))) short sh4;  // 4 x bf16 (8 B)
typedef __attribute__((ext_vector_type(4))) float f4;   // MFMA accumulator

// fold 1/sqrt(64) * log2(e) into Q so softmax is pure exp2
#define QSCALE 0.18033688011112042f

typedef const __attribute__((address_space(1))) unsigned int* gas_t;
typedef __attribute__((address_space(3))) unsigned int* las_t;
#define GLD16(g, l) __builtin_amdgcn_global_load_lds((gas_t)(g), (las_t)(l), 16, 0, 0)

static __device__ __forceinline__ unsigned short f2bf(float f) {
  unsigned u = __builtin_bit_cast(unsigned, f);
  u += 0x7fffu + ((u >> 16) & 1u);   // RNE
  return (unsigned short)(u >> 16);
}
static __device__ __forceinline__ float bf2f(unsigned short s) {
  unsigned u = ((unsigned)s) << 16;
  return __builtin_bit_cast(float, u);
}

// ---------------- kernel 1: Wt2 = W in MFMA B-fragment order ----------------
// Wt2[band][kt][lane][j] (bf16) band 0..11 (0-3 Q, 4-7 K, 8-11 V), kt 0..31,
// lane = q*16+l15 holds W[k = kt*32+q*8+j][col = band%4*16+l15].
// A B-fragment (band,kt) is 1KB CONTIGUOUS -> GLD16 staging is 8-line coalesced.
__global__ __launch_bounds__(256) void wt_kernel(const float* __restrict__ Wq,
                                                 const float* __restrict__ Wk,
                                                 const float* __restrict__ Wv,
                                                 unsigned short* __restrict__ Wt2) {
  int blk = blockIdx.x;                 // 0..95
  int band = blk >> 3;                  // 0..11
  int widx = band >> 2;
  const float* W = widx == 0 ? Wq : (widx == 1 ? Wk : Wv);
  int ncol = (band & 3) * 16;
  int t = threadIdx.x;
  int kt = (blk & 7) * 4 + (t >> 6);    // 4 kt per block
  int lane = t & 63, q = lane >> 4, l15 = lane & 15;
  const float* src = W + (size_t)(kt * 32 + q * 8) * 64 + ncol + l15;
  sh8 o;
#pragma unroll
  for (int j = 0; j < 8; ++j) o[j] = (short)f2bf(src[(size_t)j * 64]);
  *(sh8*)&Wt2[((size_t)(band * 32 + kt) * 64 + lane) * 8] = o;
}

// ---------------- kernel 2: projection — R0 structure, M=16 tile, 4 blocks/CU ----------------
// The ONLY proj structure that ever performed (47 us) is R0: LDS staging via
// global_load_lds + one __syncthreads per k-step. Its limit was grid-limited
// occupancy (512 blocks = 2 blocks/CU): the barrier-locked latency chain had no
// other blocks to overlap with. This version keeps the structure bit-for-bit and:
//   (1) M=32 -> 16: grid 1024 -> 4 blocks/CU, 16 waves/CU; independent blocks'
//       barrier stalls interleave (m114 wave-level overlap).
//   (2) B staged from fragment-ordered Wt2: per-lane src = base+lane*16, 1KB
//       contiguous per GLD16 (8 lines, vs 16-segment gather before).
// LDS/buffer: A 2KB fp32 + B 12KB bf16 = 14KB; double-buffered = 28KB.
__global__ __launch_bounds__(256, 4) void proj_kernel(const float* __restrict__ in,
                                                      const unsigned short* __restrict__ Wt2,
                                                      unsigned short* __restrict__ Qg,
                                                      unsigned short* __restrict__ Kg,
                                                      unsigned short* __restrict__ Vtg) {
  __shared__ __align__(16) char lds[28672];
  int t = threadIdx.x;
  int w = t >> 6, lane = t & 63, q = lane >> 4, l15 = lane & 15;
  int m0 = blockIdx.x * 16;

  // A staging: waves 0,1 cover the 16-row x 128B k-chunk (wave w -> float seg w*4)
  const float* ga = in + (size_t)(m0 + l15) * 1024 + q * 8 + (w & 1) * 4;
  // B staging: wave w stages bands w*3..w*3+2; per-lane contiguous fragment source
  const unsigned short* gb = Wt2 + (size_t)(w * 3) * 16384 + lane * 8;

  f4 acc[3];
  f4 z = {0.f, 0.f, 0.f, 0.f};
#pragma unroll
  for (int nt = 0; nt < 3; ++nt) acc[nt] = z;

#define STAGE(kt, buf)                                                        \
  {                                                                           \
    int k0 = (kt) * 32;                                                       \
    char* base = lds + (buf) * 14336;                                         \
    if (w < 2) GLD16(ga + k0, base + w * 1024);                               \
    GLD16(gb + (kt) * 512, base + 2048 + (w * 3 + 0) * 1024);                 \
    GLD16(gb + 16384 + (kt) * 512, base + 2048 + (w * 3 + 1) * 1024);         \
    GLD16(gb + 32768 + (kt) * 512, base + 2048 + (w * 3 + 2) * 1024);         \
  }

  STAGE(0, 0);
  for (int kt = 0; kt < 32; ++kt) {
    int cur = kt & 1;
    __syncthreads();
    if (kt + 1 < 32) STAGE(kt + 1, cur ^ 1);

    const f4* Af = (const f4*)(lds + cur * 14336);
    f4 lo = Af[lane], hi = Af[64 + lane];
    sh8 a;
#pragma unroll
    for (int j = 0; j < 4; ++j) {
      a[j] = (short)f2bf(lo[j]);
      a[4 + j] = (short)f2bf(hi[j]);
    }
    const sh8* Bf = (const sh8*)(lds + cur * 14336 + 2048);
#pragma unroll
    for (int nt = 0; nt < 3; ++nt) {
      sh8 bf = Bf[(w * 3 + nt) * 64 + lane];
      acc[nt] = __builtin_amdgcn_mfma_f32_16x16x32_bf16(a, bf, acc[nt], 0, 0, 0);
    }
  }
#undef STAGE

  // epilogue: band = w*3+nt; C row = q*4+r, col = l15 within band.
  // bands 0-3 Q (scaled), 4-7 K, 8-11 V via LDS transpose (vred aliases buf0's
  // A region; last compute read buf1, and buf0 readers drained at iter-31 barrier).
  float* vred = (float*)lds;   // [16][69] fp32 = 4416 B
#pragma unroll
  for (int nt = 0; nt < 3; ++nt) {
    int band = w * 3 + nt;
#pragma unroll
    for (int r = 0; r < 4; ++r) {
      int row = q * 4 + r;
      float v = acc[nt][r];
      if (band < 4) {
        Qg[(size_t)(m0 + row) * 64 + band * 16 + l15] = f2bf(v * QSCALE);
      } else if (band < 8) {
        Kg[(size_t)(m0 + row) * 64 + (band - 4) * 16 + l15] = f2bf(v);
      } else {
        vred[row * 69 + (band - 8) * 16 + l15] = v;
      }
    }
  }
  __syncthreads();
  {
    int h = t >> 2, sl = (t & 3) * 4;
    int bb = m0 >> 12, s0 = m0 & 4095;
    sh4 vv;
#pragma unroll
    for (int j = 0; j < 4; ++j) vv[j] = (short)f2bf(vred[(sl + j) * 69 + h]);
    *(sh4*)&Vtg[(((size_t)(bb * 64 + h)) << 12) + s0 + sl] = vv;
  }
}

// ---------------- kernel 3: causal flash attention, S^T trick, split-K ----------------
__global__ __launch_bounds__(256, 4) void attn_split(const unsigned short* __restrict__ Qg,
                                                     const unsigned short* __restrict__ Kg,
                                                     const unsigned short* __restrict__ Vtg,
                                                     unsigned short* __restrict__ Opart,
                                                     float* __restrict__ Lpart) {
  __shared__ unsigned short Ks[64 * 72];
  __shared__ unsigned short Vs[64 * 72];
  __shared__ unsigned short Pw[4 * 16 * 72];
  int t = threadIdx.x;
  int b = blockIdx.y;
  int qt = 63 - (int)(blockIdx.x >> 3);  // heavy q-tiles first (LPT)
  int sp = blockIdx.x & 7;
  int wave = t >> 6, lane = t & 63, quad = lane >> 4, l15 = lane & 15;
  unsigned short* Pws = Pw + wave * 16 * 72;

  int qrow0 = qt * 64 + wave * 16;
  size_t pbase = ((size_t)sp * 4 + b) * 4096;

  int nkt = qt + 1;
  int chunk = (nkt + NS - 1) / NS;
  int t0 = sp * chunk, t1 = min(nkt, t0 + chunk);
  if (t0 >= t1) {  // empty chunk: zero partials
#pragma unroll
    for (int r = 0; r < 4; ++r) {
      size_t row = pbase + qrow0 + quad * 4 + r;
#pragma unroll
      for (int ht = 0; ht < 4; ++ht) Opart[row * 64 + ht * 16 + l15] = 0;
      if (l15 == 0) Lpart[row] = 0.f;
    }
    return;
  }

  sh8 qa[2];
#pragma unroll
  for (int ks = 0; ks < 2; ++ks)
    qa[ks] = *(const sh8*)&Qg[(size_t)((b << 12) + qrow0 + l15) * 64 + ks * 32 + quad * 8];

  sh8 ones;
#pragma unroll
  for (int j = 0; j < 8; ++j) ones[j] = (short)0x3F80;  // bf16 1.0

  f4 o[5];  // o[0..3]: O accumulator; o[4]: row-sum (P * ones)
  f4 z = {0.f, 0.f, 0.f, 0.f};
#pragma unroll
  for (int ht = 0; ht < 5; ++ht) o[ht] = z;

  // staging geometry: thread covers chunks c0=t, c1=t+256; row=c>>3, off=(c&7)*8
  int r0 = t >> 3, o0 = (t & 7) * 8;
  int r1 = (t + 256) >> 3, o1 = ((t + 256) & 7) * 8;
  const unsigned short* kg0 = Kg + (size_t)((b << 12) + r0) * 64 + o0;
  const unsigned short* kg1 = Kg + (size_t)((b << 12) + r1) * 64 + o1;
  const unsigned short* vg0 = Vtg + (((size_t)(b * 64 + r0)) << 12) + o0;
  const unsigned short* vg1 = Vtg + (((size_t)(b * 64 + r1)) << 12) + o1;

  sh8 kr0, kr1, vr0, vr1;
  {
    size_t ko = (size_t)t0 * 64 * 64;
    kr0 = *(const sh8*)(kg0 + ko); kr1 = *(const sh8*)(kg1 + ko);
    vr0 = *(const sh8*)(vg0 + t0 * 64); vr1 = *(const sh8*)(vg1 + t0 * 64);
  }

  for (int kt = t0; kt < t1; ++kt) {
    __syncthreads();                      // prev-iter LDS reads done
    *(sh8*)&Ks[r0 * 72 + o0] = kr0;
    *(sh8*)&Ks[r1 * 72 + o1] = kr1;
    *(sh8*)&Vs[r0 * 72 + o0] = vr0;
    *(sh8*)&Vs[r1 * 72 + o1] = vr1;
    if (kt + 1 < t1) {                    // prefetch next tile into regs
      size_t ko = (size_t)(kt + 1) * 64 * 64;
      kr0 = *(const sh8*)(kg0 + ko); kr1 = *(const sh8*)(kg1 + ko);
      vr0 = *(const sh8*)(vg0 + (kt + 1) * 64); vr1 = *(const sh8*)(vg1 + (kt + 1) * 64);
    }
    __syncthreads();                      // Ks/Vs visible

    // S^T = K * Q^T: st[nt] lane(quad,l15) reg r = S[qrow0+l15][kt*64+nt*16+quad*4+r]
    f4 st[4];
#pragma unroll
    for (int nt = 0; nt < 4; ++nt) st[nt] = z;
#pragma unroll
    for (int ks = 0; ks < 2; ++ks) {
#pragma unroll
      for (int nt = 0; nt < 4; ++nt) {
        sh8 kb = *(const sh8*)&Ks[(nt * 16 + l15) * 72 + ks * 32 + quad * 8];
        st[nt] = __builtin_amdgcn_mfma_f32_16x16x32_bf16(kb, qa[ks], st[nt], 0, 0, 0);
      }
    }

    if (kt == nkt - 1) {  // causal mask on the global diagonal tile
      int qrow = qrow0 + l15;
#pragma unroll
      for (int nt = 0; nt < 4; ++nt) {
        int key0 = kt * 64 + nt * 16 + quad * 4;
#pragma unroll
        for (int r = 0; r < 4; ++r)
          if (key0 + r > qrow) st[nt][r] = -__builtin_inff();
      }
    }

    // static-max softmax: P = exp2(S); pack 4 contiguous keys -> one b64 LDS write
#pragma unroll
    for (int nt = 0; nt < 4; ++nt) {
      sh4 pk;
#pragma unroll
      for (int r = 0; r < 4; ++r) pk[r] = (short)f2bf(exp2f(st[nt][r]));
      *(sh4*)&Pws[l15 * 72 + nt * 16 + quad * 4] = pk;
    }
    asm volatile("s_waitcnt lgkmcnt(0)" ::: "memory");

#pragma unroll
    for (int ks = 0; ks < 2; ++ks) {
      sh8 pa = *(const sh8*)&Pws[l15 * 72 + ks * 32 + quad * 8];
#pragma unroll
      for (int ht = 0; ht < 4; ++ht) {
        sh8 vb = *(const sh8*)&Vs[(ht * 16 + l15) * 72 + ks * 32 + quad * 8];
        o[ht] = __builtin_amdgcn_mfma_f32_16x16x32_bf16(pa, vb, o[ht], 0, 0, 0);
      }
      o[4] = __builtin_amdgcn_mfma_f32_16x16x32_bf16(pa, ones, o[4], 0, 0, 0);
    }
  }

  // write partials (unnormalized O, bf16; L fp32)
#pragma unroll
  for (int r = 0; r < 4; ++r) {
    size_t row = pbase + qrow0 + quad * 4 + r;
#pragma unroll
    for (int ht = 0; ht < 4; ++ht)
      Opart[row * 64 + ht * 16 + l15] = f2bf(o[ht][r]);
    if (l15 == 0) Lpart[row] = o[4][r];
  }
}

// ---------------- kernel 4: combine split partials ----------------
__global__ __launch_bounds__(256) void attn_combine(const unsigned short* __restrict__ Opart,
                                                    const float* __restrict__ Lpart,
                                                    float* __restrict__ out) {
  int t = threadIdx.x;
  int rg = blockIdx.x * 4 + (t >> 6);  // global row 0..16383
  int lane = t & 63;
  float acc = 0.f, L = 0.f;
#pragma unroll
  for (int s = 0; s < NS; ++s) {
    L += Lpart[(size_t)s * 16384 + rg];
    acc += bf2f(Opart[((size_t)s * 16384 + rg) * 64 + lane]);
  }
  out[(size_t)rg * 64 + lane] = acc / L;
}

extern "C" void kernel_launch(void* const* d_in, const int* in_sizes, int n_in,
                              void* d_out, int out_size, void* d_ws, size_t ws_size,
                              hipStream_t stream) {
  const float* in = (const float*)d_in[0];
  const float* Wq = (const float*)d_in[1];
  const float* Wk = (const float*)d_in[2];
  const float* Wv = (const float*)d_in[3];
  float* out = (float*)d_out;

  char* ws = (char*)d_ws;
  unsigned short* Wt2   = (unsigned short*)ws;                 // 393,216 B
  unsigned short* Qg    = (unsigned short*)(ws + 393216);      // 2 MiB
  unsigned short* Kg    = (unsigned short*)(ws + 2490368);     // 2 MiB
  unsigned short* Vtg   = (unsigned short*)(ws + 4587520);     // 2 MiB
  unsigned short* Opart = (unsigned short*)(ws + 6684672);     // 16,777,216 B
  float*          Lpart = (float*)(ws + 23461888);             // 524,288 B
  // total ws use ~24 MiB

  hipLaunchKernelGGL(wt_kernel, dim3(96), dim3(256), 0, stream, Wq, Wk, Wv, Wt2);
  hipLaunchKernelGGL(proj_kernel, dim3(1024), dim3(256), 0, stream, in, Wt2, Qg, Kg, Vtg);
  hipLaunchKernelGGL(attn_split, dim3(64 * NS, 4), dim3(256), 0, stream,
                     Qg, Kg, Vtg, Opart, Lpart);
  hipLaunchKernelGGL(attn_combine, dim3(4096), dim3(256), 0, stream,
                     Opart, Lpart, out);
}